// Round 2
// baseline (1079.055 us; speedup 1.0000x reference)
//
#include <hip/hip_runtime.h>
#include <hip/hip_bf16.h>

#define C_DIM 128
#define TWO_C 256
#define FC    32
#define T_DIM 512

typedef unsigned int   u32;
typedef unsigned short u16;
typedef short bf16x8 __attribute__((ext_vector_type(8)));
typedef float f32x4  __attribute__((ext_vector_type(4)));

__device__ __forceinline__ float fast_erf(float x) {
    // Abramowitz & Stegun 7.1.26, max abs err 1.5e-7; exp via hw v_exp
    float a = fabsf(x);
    float t = 1.0f / (1.0f + 0.3275911f * a);
    float p = t * (0.254829592f + t * (-0.284496736f + t * (1.421413741f +
              t * (-1.453152027f + t * 1.061405429f))));
    float y = 1.0f - p * __expf(-a * a);
    return copysignf(y, x);
}
__device__ __forceinline__ float gelu_f(float x) {
    return 0.5f * x * (1.0f + fast_erf(x * 0.70710678118654752440f));
}
__device__ __forceinline__ u32 f2bf_bits(float x) {
    u32 u = __float_as_uint(x);
    return (u + 0x7fffu + ((u >> 16) & 1u)) >> 16;   // RNE f32->bf16
}

// ---------- time modulation: tm = gelu(t) @ tw + tb, both mlps in one grid ----------
__global__ __launch_bounds__(256) void k_tmod(const float* __restrict__ t,
                                              const float* __restrict__ tw1,
                                              const float* __restrict__ tb1,
                                              float* __restrict__ tm1,
                                              const float* __restrict__ tw2,
                                              const float* __restrict__ tb2,
                                              float* __restrict__ tm2) {
    const float* tw = blockIdx.y ? tw2 : tw1;
    const float* tb = blockIdx.y ? tb2 : tb1;
    float*       tm = blockIdx.y ? tm2 : tm1;
    __shared__ float gt[T_DIM];
    int b = blockIdx.x;
    for (int k = threadIdx.x; k < T_DIM; k += 256)
        gt[k] = gelu_f(t[(size_t)b * T_DIM + k]);
    __syncthreads();
    int j = threadIdx.x;
    float acc = tb[j];
    for (int k = 0; k < T_DIM; ++k)
        acc += gt[k] * tw[(size_t)k * TWO_C + j];
    tm[(size_t)b * TWO_C + j] = acc;
}

// ---------- modulate: out = LN(in)*(1+scale) + shift ----------
template <bool BF16OUT>
__global__ __launch_bounds__(C_DIM) void k_mod(const float* __restrict__ in,
                                               const float* __restrict__ lns,
                                               const float* __restrict__ lnb,
                                               const float* __restrict__ tm,
                                               void* __restrict__ outp, int q) {
    int n = blockIdx.x, c = threadIdx.x;
    size_t o = (size_t)n * C_DIM + c;
    float v = in[o];
    float s1 = v, s2 = v * v;
#pragma unroll
    for (int off = 32; off > 0; off >>= 1) {
        s1 += __shfl_down(s1, off);
        s2 += __shfl_down(s2, off);
    }
    __shared__ float red[4];
    if ((c & 63) == 0) { red[(c >> 6) * 2] = s1; red[(c >> 6) * 2 + 1] = s2; }
    __syncthreads();
    float mean = (red[0] + red[2]) * (1.0f / C_DIM);
    float ex2  = (red[1] + red[3]) * (1.0f / C_DIM);
    float r    = rsqrtf(ex2 - mean * mean + 1e-5f);
    int b = n / q;
    float scale = tm[(size_t)b * TWO_C + c];
    float shift = tm[(size_t)b * TWO_C + C_DIM + c];
    float h = (v - mean) * r * lns[c] + lnb[c];
    float res = h * (1.0f + scale) + shift;
    if (BF16OUT) ((u16*)outp)[o] = (u16)f2bf_bits(res);
    else         ((float*)outp)[o] = res;
}

// ---------- counting sort by dst ----------
__global__ void k_hist(const int* __restrict__ dst, int* __restrict__ cnt, int E) {
    int e = blockIdx.x * 256 + threadIdx.x;
    if (e < E) atomicAdd(&cnt[dst[e]], 1);
}

__global__ __launch_bounds__(1024) void k_scan(int* __restrict__ data,
                                               int* __restrict__ cursor, int N) {
    __shared__ int tot[1024];
    int t = threadIdx.x;
    const int PER = 32;
    int base = t * PER;
    int loc[PER];
    int s = 0;
#pragma unroll
    for (int i = 0; i < PER; ++i) {
        int idx = base + i;
        int v = (idx < N) ? data[idx] : 0;
        loc[i] = s; s += v;
    }
    tot[t] = s;
    __syncthreads();
    for (int off = 1; off < 1024; off <<= 1) {
        int v = (t >= off) ? tot[t - off] : 0;
        __syncthreads();
        tot[t] += v;
        __syncthreads();
    }
    int bb = (t == 0) ? 0 : tot[t - 1];
#pragma unroll
    for (int i = 0; i < PER; ++i) {
        int idx = base + i;
        if (idx < N) { int v = bb + loc[i]; data[idx] = v; cursor[idx] = v; }
    }
    if (t == 1023) data[N] = tot[1023];
}

__global__ void k_scatter(const int* __restrict__ dst, int* __restrict__ cursor,
                          int* __restrict__ sorted, int E) {
    int e = blockIdx.x * 256 + threadIdx.x;
    if (e < E) {
        int pos = atomicAdd(&cursor[dst[e]], 1);
        sorted[pos] = e;
    }
}

// ---------- edge kernel-MLP layers 1..2 -> bf16, sorted order ----------
__global__ __launch_bounds__(256) void k_edgek2(
        const int* __restrict__ sorted_eid,
        const int* __restrict__ ei_src,
        const float* __restrict__ ea,
        const float* __restrict__ w1, const float* __restrict__ b1,
        const float* __restrict__ w2, const float* __restrict__ b2,
        u16* __restrict__ k2s, int* __restrict__ src_sorted, int E) {
    int p = blockIdx.x * 256 + threadIdx.x;
    if (p >= E) return;
    int eid = sorted_eid[p];
    src_sorted[p] = ei_src[eid];
    float ax = ea[(size_t)eid * 2 + 0];
    float ay = ea[(size_t)eid * 2 + 1];
    float k1[FC];
#pragma unroll
    for (int i = 0; i < FC; ++i)
        k1[i] = gelu_f(ax * w1[i] + ay * w1[FC + i] + b1[i]);
    float k2v[FC];
#pragma unroll
    for (int j = 0; j < FC; ++j) {
        float acc = b2[j];
#pragma unroll
        for (int i = 0; i < FC; ++i)
            acc += k1[i] * w2[i * FC + j];
        k2v[j] = gelu_f(acc);
    }
    u32 pk[FC / 2];
#pragma unroll
    for (int m = 0; m < FC / 2; ++m)
        pk[m] = f2bf_bits(k2v[2 * m]) | (f2bf_bits(k2v[2 * m + 1]) << 16);
    uint4* o = (uint4*)(k2s + (size_t)p * FC);
#pragma unroll
    for (int qq = 0; qq < FC / 8; ++qq)
        o[qq] = make_uint4(pk[qq * 4 + 0], pk[qq * 4 + 1],
                           pk[qq * 4 + 2], pk[qq * 4 + 3]);
}

// ---------- prep: frag-major bf16 layouts for w1 (mlp), w2 (mlp), w3 (kernel) ----------
// frag element j of lane l, frag f: value = W[k = ks*32 + 8*(l>>4) + j][n = nt*16 + (l&15)]
__global__ __launch_bounds__(256) void k_prep(const float* __restrict__ mw1,
                                              const float* __restrict__ mw2,
                                              const float* __restrict__ kw3,
                                              u16* __restrict__ w1f,
                                              u16* __restrict__ w2f,
                                              u16* __restrict__ w3f) {
    int t = blockIdx.x * 256 + threadIdx.x;
    if (t < 32768) {            // w1f: [nt16][ks4][64][8], W = mw1 [128][256]
        int j = t & 7, l = (t >> 3) & 63, f = t >> 9;
        int ks = f & 3, nt = f >> 2;
        int k = ks * 32 + ((l >> 4) << 3) + j, n = nt * 16 + (l & 15);
        w1f[t] = (u16)f2bf_bits(mw1[(size_t)k * TWO_C + n]);
    } else if (t < 65536) {     // w2f: [nt8][ks8][64][8], W = mw2 [256][128]
        int t2 = t - 32768;
        int j = t2 & 7, l = (t2 >> 3) & 63, f = t2 >> 9;
        int ks = f & 7, nt = f >> 3;
        int k = ks * 32 + ((l >> 4) << 3) + j, n = nt * 16 + (l & 15);
        w2f[t2] = (u16)f2bf_bits(mw2[(size_t)k * C_DIM + n]);
    } else if (t < 65536 + 4096) {  // w3f: [nt8][64][8], W = kw3 [32][128]
        int t3 = t - 65536;
        int j = t3 & 7, l = (t3 >> 3) & 63, nt = t3 >> 9;
        int k = ((l >> 4) << 3) + j, n = nt * 16 + (l & 15);
        w3f[t3] = (u16)f2bf_bits(kw3[(size_t)k * C_DIM + n]);
    }
}

// ---------- conv (MFMA): W=k2@w3+b3 on matrix cores, gather h, fused LN2+mod ----------
__global__ __launch_bounds__(256) void k_conv3(
        const float* __restrict__ feats,
        const float* __restrict__ h_mod,      // (N+1) rows, row N = zeros
        const float* __restrict__ normv,
        const int* __restrict__ start,
        const int* __restrict__ src_sorted,
        const u16* __restrict__ k2h,          // [E][32] bf16 (sorted order)
        const u16* __restrict__ w3f,          // frag-major
        const float* __restrict__ b3,
        const float* __restrict__ cbias,
        const float* __restrict__ tm2,
        const float* __restrict__ ln2s, const float* __restrict__ ln2b,
        float* __restrict__ xio,              // out: x = feats + conv (d_out)
        u16* __restrict__ xmb,                // out: modulate2(x) bf16
        int N, int q) {
    int l  = threadIdx.x & 63;
    int n  = blockIdx.x * 4 + (threadIdx.x >> 6);
    int lr = l & 15, g = l >> 4;

    bf16x8 wb[8];
#pragma unroll
    for (int nt = 0; nt < 8; ++nt)
        wb[nt] = *(const bf16x8*)(w3f + ((size_t)nt * 64 + l) * 8);
    f32x4 binit[8];
#pragma unroll
    for (int nt = 0; nt < 8; ++nt) {
        float bv = b3[nt * 16 + lr];
        binit[nt][0] = bv; binit[nt][1] = bv; binit[nt][2] = bv; binit[nt][3] = bv;
    }

    int s = start[n], e = start[n + 1];
    float acc[8] = {0.f, 0.f, 0.f, 0.f, 0.f, 0.f, 0.f, 0.f};

    for (int p0 = s; p0 < e; p0 += 16) {
        int pa = p0 + lr;                       // A row lr = edge p0+lr
        bf16x8 a = {0, 0, 0, 0, 0, 0, 0, 0};
        if (pa < e) a = *(const bf16x8*)(k2h + (size_t)pa * FC + g * 8);
        int srcv[4];
#pragma unroll
        for (int r = 0; r < 4; ++r) {           // D row 4g+r = edge p0+4g+r
            int pp = p0 + 4 * g + r;
            srcv[r] = (pp < e) ? src_sorted[pp] : N;   // row N of h_mod = zeros
        }
#pragma unroll
        for (int nt = 0; nt < 8; ++nt) {
            f32x4 w = __builtin_amdgcn_mfma_f32_16x16x32_bf16(a, wb[nt], binit[nt], 0, 0, 0);
#pragma unroll
            for (int r = 0; r < 4; ++r)
                acc[nt] += w[r] * h_mod[(size_t)srcv[r] * C_DIM + nt * 16 + lr];
        }
    }
#pragma unroll
    for (int nt = 0; nt < 8; ++nt) {            // reduce over the 4 k-groups
        acc[nt] += __shfl_xor(acc[nt], 16, 64);
        acc[nt] += __shfl_xor(acc[nt], 32, 64);
    }

    float rnv = 1.0f / normv[n];
    float xv[8], m1 = 0.f, m2 = 0.f;
#pragma unroll
    for (int nt = 0; nt < 8; ++nt) {
        int c = nt * 16 + lr;
        float v = feats[(size_t)n * C_DIM + c] + (acc[nt] + cbias[c]) * rnv;
        xv[nt] = v; m1 += v; m2 += v * v;
    }
#pragma unroll
    for (int off = 1; off <= 8; off <<= 1) {
        m1 += __shfl_xor(m1, off, 64);
        m2 += __shfl_xor(m2, off, 64);
    }
    float mean = m1 * (1.0f / C_DIM);
    float rstd = rsqrtf(m2 * (1.0f / C_DIM) - mean * mean + 1e-5f);
    int b = n / q;
    bool wr = (g == 0);
#pragma unroll
    for (int nt = 0; nt < 8; ++nt) {
        int c = nt * 16 + lr;
        size_t o = (size_t)n * C_DIM + c;
        float sc = tm2[(size_t)b * TWO_C + c];
        float sh = tm2[(size_t)b * TWO_C + C_DIM + c];
        float h2 = ((xv[nt] - mean) * rstd * ln2s[c] + ln2b[c]) * (1.0f + sc) + sh;
        if (wr) { xio[o] = xv[nt]; xmb[o] = (u16)f2bf_bits(h2); }
    }
}

// ---------- FFN (MFMA): out += gelu(xm@w1+b1)@w2+b2 ; per-wave 16 rows ----------
__global__ __launch_bounds__(256) void k_ffn2(const u16* __restrict__ xm,
                                              const u16* __restrict__ w1f,
                                              const float* __restrict__ b1,
                                              const u16* __restrict__ w2f,
                                              const float* __restrict__ b2,
                                              float* __restrict__ xio, int N) {
    __shared__ u16 sm[4][4096];                 // per-wave m tile [16][256] bf16, 8 KB
    int tid = threadIdx.x, w = tid >> 6, l = tid & 63;
    int lr = l & 15, g = l >> 4;
    int n0 = blockIdx.x * 64 + w * 16;
    u16* smw = sm[w];

    // GEMM1: m = xm[16 rows x 128] @ w1[128 x 256]
    bf16x8 a[4];
    const u16* xrow = xm + (size_t)(n0 + lr) * C_DIM;
#pragma unroll
    for (int ks = 0; ks < 4; ++ks)
        a[ks] = *(const bf16x8*)(xrow + ks * 32 + g * 8);
    f32x4 acc[16];
#pragma unroll
    for (int nt = 0; nt < 16; ++nt) {
        float bv = b1[nt * 16 + lr];
        acc[nt][0] = bv; acc[nt][1] = bv; acc[nt][2] = bv; acc[nt][3] = bv;
    }
#pragma unroll
    for (int nt = 0; nt < 16; ++nt)
#pragma unroll
        for (int ks = 0; ks < 4; ++ks) {
            bf16x8 bfr = *(const bf16x8*)(w1f + ((size_t)(nt * 4 + ks) * 64 + l) * 8);
            acc[nt] = __builtin_amdgcn_mfma_f32_16x16x32_bf16(a[ks], bfr, acc[nt], 0, 0, 0);
        }
    // gelu -> LDS (XOR-swizzled u16 scatter)
#pragma unroll
    for (int nt = 0; nt < 16; ++nt)
#pragma unroll
        for (int r = 0; r < 4; ++r) {
            int row = 4 * g + r, col = nt * 16 + lr;
            int byte = row * 512 + ((col * 2) ^ ((row & 7) << 4));
            smw[byte >> 1] = (u16)f2bf_bits(gelu_f(acc[nt][r]));
        }
    // GEMM2: h2 = m[16 x 256] @ w2[256 x 128]  (same-wave LDS dependency)
    f32x4 acc2[8];
#pragma unroll
    for (int nt = 0; nt < 8; ++nt) {
        float bv = b2[nt * 16 + lr];
        acc2[nt][0] = bv; acc2[nt][1] = bv; acc2[nt][2] = bv; acc2[nt][3] = bv;
    }
#pragma unroll
    for (int ks = 0; ks < 8; ++ks) {
        int byte = lr * 512 + ((ks * 64 + g * 16) ^ ((lr & 7) << 4));
        bf16x8 a2 = *(const bf16x8*)(smw + (byte >> 1));
#pragma unroll
        for (int nt = 0; nt < 8; ++nt) {
            bf16x8 bfr = *(const bf16x8*)(w2f + ((size_t)(nt * 8 + ks) * 64 + l) * 8);
            acc2[nt] = __builtin_amdgcn_mfma_f32_16x16x32_bf16(a2, bfr, acc2[nt], 0, 0, 0);
        }
    }
#pragma unroll
    for (int nt = 0; nt < 8; ++nt)
#pragma unroll
        for (int r = 0; r < 4; ++r) {
            size_t o = (size_t)(n0 + 4 * g + r) * C_DIM + nt * 16 + lr;
            xio[o] += acc2[nt][r];
        }
}

// ---------- atomic fallback ----------
__global__ __launch_bounds__(256) void k_edge_atomic(
        const int* __restrict__ ei, const float* __restrict__ ea,
        const float* __restrict__ w1, const float* __restrict__ b1,
        const float* __restrict__ w2, const float* __restrict__ b2,
        const float* __restrict__ w3, const float* __restrict__ b3,
        const float* __restrict__ h_mod, float* __restrict__ xacc, int E) {
    int e = blockIdx.x * 256 + threadIdx.x;
    if (e >= E) return;
    int src = ei[e], dst = ei[E + e];
    float ax = ea[(size_t)e * 2], ay = ea[(size_t)e * 2 + 1];
    float k1[FC];
#pragma unroll
    for (int i = 0; i < FC; ++i) k1[i] = gelu_f(ax * w1[i] + ay * w1[FC + i] + b1[i]);
    float k2v[FC];
#pragma unroll
    for (int j = 0; j < FC; ++j) {
        float acc = b2[j];
#pragma unroll
        for (int i = 0; i < FC; ++i) acc += k1[i] * w2[i * FC + j];
        k2v[j] = gelu_f(acc);
    }
    const float* hrow = h_mod + (size_t)src * C_DIM;
    float* orow = xacc + (size_t)dst * C_DIM;
    for (int c = 0; c < C_DIM; ++c) {
        float wv = b3[c];
#pragma unroll
        for (int j = 0; j < FC; ++j) wv += k2v[j] * w3[j * C_DIM + c];
        atomicAdd(&orow[c], wv * hrow[c]);
    }
}

__global__ void k_finish(const float* __restrict__ feats, const float* __restrict__ cbias,
                         const float* __restrict__ normv, float* __restrict__ xbuf, int NC) {
    int i = blockIdx.x * 256 + threadIdx.x;
    if (i >= NC) return;
    int c = i & (C_DIM - 1);
    int n = i >> 7;
    xbuf[i] = feats[i] + (xbuf[i] + cbias[c]) / normv[n];
}

extern "C" void kernel_launch(void* const* d_in, const int* in_sizes, int n_in,
                              void* d_out, int out_size, void* d_ws, size_t ws_size,
                              hipStream_t stream) {
    const float* feats = (const float*)d_in[0];
    const int*   ei    = (const int*)d_in[1];
    const float* ea    = (const float*)d_in[2];
    const float* t     = (const float*)d_in[3];
    const float* normv = (const float*)d_in[4];
    const float* ln1s  = (const float*)d_in[5];
    const float* ln1b  = (const float*)d_in[6];
    const float* ln2s  = (const float*)d_in[7];
    const float* ln2b  = (const float*)d_in[8];
    const float* tw1   = (const float*)d_in[9];
    const float* tb1   = (const float*)d_in[10];
    const float* tw2   = (const float*)d_in[11];
    const float* tb2   = (const float*)d_in[12];
    const float* kw1   = (const float*)d_in[13];
    const float* kb1   = (const float*)d_in[14];
    const float* kw2   = (const float*)d_in[15];
    const float* kb2   = (const float*)d_in[16];
    const float* kw3   = (const float*)d_in[17];
    const float* kb3   = (const float*)d_in[18];
    const float* cbias = (const float*)d_in[19];
    const float* mw1   = (const float*)d_in[20];
    const float* mb1   = (const float*)d_in[21];
    const float* mw2   = (const float*)d_in[22];
    const float* mb2   = (const float*)d_in[23];
    float* out = (float*)d_out;

    const int N = in_sizes[0] / C_DIM;
    const int E = in_sizes[1] / 2;
    const int B = in_sizes[3] / T_DIM;
    const int q = N / B;

    char* wp = (char*)d_ws;
    auto alloc = [&](size_t bytes) -> char* {
        char* p = wp; wp += (bytes + 255) & ~(size_t)255; return p;
    };
    float* tm1        = (float*)alloc((size_t)B * TWO_C * 4);
    float* tm2        = (float*)alloc((size_t)B * TWO_C * 4);
    float* h_mod      = (float*)alloc(((size_t)N + 1) * C_DIM * 4);  // +1 zero row
    u16*   xmb        = (u16*)alloc((size_t)N * C_DIM * 2);
    u16*   w1f        = (u16*)alloc((size_t)C_DIM * TWO_C * 2);
    u16*   w2f        = (u16*)alloc((size_t)TWO_C * C_DIM * 2);
    u16*   w3f        = (u16*)alloc((size_t)FC * C_DIM * 2);
    int*   cnt        = (int*)alloc(((size_t)N + 1) * 4);
    int*   cursor     = (int*)alloc((size_t)N * 4);
    int*   sorted     = (int*)alloc((size_t)E * 4);
    int*   src_sorted = (int*)alloc((size_t)E * 4);
    size_t fixed = (size_t)(wp - (char*)d_ws);
    bool can_sort = ws_size >= fixed + ((size_t)E + 16) * FC * 2;
    u16* k2h = (u16*)alloc(((size_t)E + 16) * FC * 2);

    const int eb = (E + 255) / 256;

    k_tmod<<<dim3(B, 2), 256, 0, stream>>>(t, tw1, tb1, tm1, tw2, tb2, tm2);
    k_mod<false><<<N, C_DIM, 0, stream>>>(feats, ln1s, ln1b, tm1, h_mod, q);
    k_prep<<<(65536 + 4096 + 255) / 256, 256, 0, stream>>>(mw1, mw2, kw3, w1f, w2f, w3f);
    hipMemsetAsync(h_mod + (size_t)N * C_DIM, 0, C_DIM * 4, stream);  // zero row N

    if (can_sort) {
        hipMemsetAsync(cnt, 0, ((size_t)N + 1) * 4, stream);
        k_hist<<<eb, 256, 0, stream>>>(ei + E, cnt, E);
        k_scan<<<1, 1024, 0, stream>>>(cnt, cursor, N);
        k_scatter<<<eb, 256, 0, stream>>>(ei + E, cursor, sorted, E);
        k_edgek2<<<eb, 256, 0, stream>>>(sorted, ei, ea, kw1, kb1, kw2, kb2,
                                         k2h, src_sorted, E);
        k_conv3<<<N / 4, 256, 0, stream>>>(feats, h_mod, normv, cnt, src_sorted,
                                           k2h, w3f, kb3, cbias, tm2, ln2s, ln2b,
                                           out, xmb, N, q);
    } else {
        hipMemsetAsync(out, 0, (size_t)N * C_DIM * 4, stream);
        k_edge_atomic<<<eb, 256, 0, stream>>>(ei, ea, kw1, kb1, kw2, kb2, kw3, kb3,
                                              h_mod, out, E);
        int nc = N * C_DIM;
        k_finish<<<(nc + 255) / 256, 256, 0, stream>>>(feats, cbias, normv, out, nc);
        k_mod<true><<<N, C_DIM, 0, stream>>>(out, ln2s, ln2b, tm2, xmb, q);
    }

    k_ffn2<<<N / 64, 256, 0, stream>>>(xmb, w1f, mb1, w2f, mb2, out, N);
}

// Round 3
// 448.947 us; speedup vs baseline: 2.4035x; 2.4035x over previous
//
#include <hip/hip_runtime.h>
#include <hip/hip_bf16.h>

#define C_DIM 128
#define TWO_C 256
#define FC    32
#define T_DIM 512

typedef unsigned int   u32;
typedef unsigned short u16;
typedef short bf16x8 __attribute__((ext_vector_type(8)));
typedef float f32x4  __attribute__((ext_vector_type(4)));

__device__ __forceinline__ float fast_rcp(float x) {
    return __builtin_amdgcn_rcpf(x);          // v_rcp_f32, ~1 ULP
}
__device__ __forceinline__ float fast_erf(float x) {
    // Abramowitz & Stegun 7.1.26, max abs err 1.5e-7; v_rcp + v_exp, no div sequence
    float a = fabsf(x);
    float t = fast_rcp(1.0f + 0.3275911f * a);
    float p = t * (0.254829592f + t * (-0.284496736f + t * (1.421413741f +
              t * (-1.453152027f + t * 1.061405429f))));
    float y = 1.0f - p * __expf(-a * a);
    return copysignf(y, x);
}
__device__ __forceinline__ float gelu_f(float x) {
    return 0.5f * x * (1.0f + fast_erf(x * 0.70710678118654752440f));
}
__device__ __forceinline__ u32 f2bf_bits(float x) {
    u32 u = __float_as_uint(x);
    return (u + 0x7fffu + ((u >> 16) & 1u)) >> 16;   // RNE f32->bf16
}

// ---------- time modulation: tm = gelu(t) @ tw + tb, both mlps in one grid ----------
__global__ __launch_bounds__(256) void k_tmod(const float* __restrict__ t,
                                              const float* __restrict__ tw1,
                                              const float* __restrict__ tb1,
                                              float* __restrict__ tm1,
                                              const float* __restrict__ tw2,
                                              const float* __restrict__ tb2,
                                              float* __restrict__ tm2) {
    const float* tw = blockIdx.y ? tw2 : tw1;
    const float* tb = blockIdx.y ? tb2 : tb1;
    float*       tm = blockIdx.y ? tm2 : tm1;
    __shared__ float gt[T_DIM];
    int b = blockIdx.x;
    for (int k = threadIdx.x; k < T_DIM; k += 256)
        gt[k] = gelu_f(t[(size_t)b * T_DIM + k]);
    __syncthreads();
    int j = threadIdx.x;
    float acc = tb[j];
    for (int k = 0; k < T_DIM; ++k)
        acc += gt[k] * tw[(size_t)k * TWO_C + j];
    tm[(size_t)b * TWO_C + j] = acc;
}

// ---------- modulate: out = LN(in)*(1+scale) + shift ----------
template <bool BF16OUT>
__global__ __launch_bounds__(C_DIM) void k_mod(const float* __restrict__ in,
                                               const float* __restrict__ lns,
                                               const float* __restrict__ lnb,
                                               const float* __restrict__ tm,
                                               void* __restrict__ outp, int q) {
    int n = blockIdx.x, c = threadIdx.x;
    size_t o = (size_t)n * C_DIM + c;
    float v = in[o];
    float s1 = v, s2 = v * v;
#pragma unroll
    for (int off = 32; off > 0; off >>= 1) {
        s1 += __shfl_down(s1, off);
        s2 += __shfl_down(s2, off);
    }
    __shared__ float red[4];
    if ((c & 63) == 0) { red[(c >> 6) * 2] = s1; red[(c >> 6) * 2 + 1] = s2; }
    __syncthreads();
    float mean = (red[0] + red[2]) * (1.0f / C_DIM);
    float ex2  = (red[1] + red[3]) * (1.0f / C_DIM);
    float r    = rsqrtf(ex2 - mean * mean + 1e-5f);
    int b = n / q;
    float scale = tm[(size_t)b * TWO_C + c];
    float shift = tm[(size_t)b * TWO_C + C_DIM + c];
    float h = (v - mean) * r * lns[c] + lnb[c];
    float res = h * (1.0f + scale) + shift;
    if (BF16OUT) ((u16*)outp)[o] = (u16)f2bf_bits(res);
    else         ((float*)outp)[o] = res;
}

// ---------- counting sort by dst ----------
__global__ void k_hist(const int* __restrict__ dst, int* __restrict__ cnt, int E) {
    int e = blockIdx.x * 256 + threadIdx.x;
    if (e < E) atomicAdd(&cnt[dst[e]], 1);
}

__global__ __launch_bounds__(1024) void k_scan(int* __restrict__ data,
                                               int* __restrict__ cursor, int N) {
    __shared__ int tot[1024];
    int t = threadIdx.x;
    const int PER = 32;
    int base = t * PER;
    int loc[PER];
    int s = 0;
#pragma unroll
    for (int i = 0; i < PER; ++i) {
        int idx = base + i;
        int v = (idx < N) ? data[idx] : 0;
        loc[i] = s; s += v;
    }
    tot[t] = s;
    __syncthreads();
    for (int off = 1; off < 1024; off <<= 1) {
        int v = (t >= off) ? tot[t - off] : 0;
        __syncthreads();
        tot[t] += v;
        __syncthreads();
    }
    int bb = (t == 0) ? 0 : tot[t - 1];
#pragma unroll
    for (int i = 0; i < PER; ++i) {
        int idx = base + i;
        if (idx < N) { int v = bb + loc[i]; data[idx] = v; cursor[idx] = v; }
    }
    if (t == 1023) data[N] = tot[1023];
}

// rank[e] = position of edge e in dst-sorted order; also write src_sorted directly
__global__ void k_scatter(const int* __restrict__ ei, int* __restrict__ cursor,
                          int* __restrict__ rank, int* __restrict__ src_sorted, int E) {
    int e = blockIdx.x * 256 + threadIdx.x;
    if (e < E) {
        int pos = atomicAdd(&cursor[ei[E + e]], 1);
        rank[e] = pos;
        src_sorted[pos] = ei[e];
    }
}

// ---------- edge kernel-MLP layers 1..2 -> bf16, coalesced reads, scatter writes ----------
__global__ __launch_bounds__(256) void k_edgek2(
        const int* __restrict__ rank,
        const float* __restrict__ ea,
        const float* __restrict__ w1, const float* __restrict__ b1,
        const float* __restrict__ w2, const float* __restrict__ b2,
        u16* __restrict__ k2s, int E) {
    int e = blockIdx.x * 256 + threadIdx.x;
    if (e >= E) return;
    int pos = rank[e];
    float2 av = ((const float2*)ea)[e];       // coalesced 8B
    float k1[FC];
#pragma unroll
    for (int i = 0; i < FC; ++i)
        k1[i] = gelu_f(av.x * w1[i] + av.y * w1[FC + i] + b1[i]);
    float k2v[FC];
#pragma unroll
    for (int j = 0; j < FC; ++j) {
        float acc = b2[j];
#pragma unroll
        for (int i = 0; i < FC; ++i)
            acc += k1[i] * w2[i * FC + j];
        k2v[j] = gelu_f(acc);
    }
    u32 pk[FC / 2];
#pragma unroll
    for (int m = 0; m < FC / 2; ++m)
        pk[m] = f2bf_bits(k2v[2 * m]) | (f2bf_bits(k2v[2 * m + 1]) << 16);
    uint4* o = (uint4*)(k2s + (size_t)pos * FC);   // one 64B line per edge
#pragma unroll
    for (int qq = 0; qq < FC / 8; ++qq)
        o[qq] = make_uint4(pk[qq * 4 + 0], pk[qq * 4 + 1],
                           pk[qq * 4 + 2], pk[qq * 4 + 3]);
}

// ---------- prep: frag-major bf16 layouts for w1 (mlp), w2 (mlp), w3 (kernel) ----------
__global__ __launch_bounds__(256) void k_prep(const float* __restrict__ mw1,
                                              const float* __restrict__ mw2,
                                              const float* __restrict__ kw3,
                                              u16* __restrict__ w1f,
                                              u16* __restrict__ w2f,
                                              u16* __restrict__ w3f) {
    int t = blockIdx.x * 256 + threadIdx.x;
    if (t < 32768) {            // w1f: [nt16][ks4][64][8], W = mw1 [128][256]
        int j = t & 7, l = (t >> 3) & 63, f = t >> 9;
        int ks = f & 3, nt = f >> 2;
        int k = ks * 32 + ((l >> 4) << 3) + j, n = nt * 16 + (l & 15);
        w1f[t] = (u16)f2bf_bits(mw1[(size_t)k * TWO_C + n]);
    } else if (t < 65536) {     // w2f: [nt8][ks8][64][8], W = mw2 [256][128]
        int t2 = t - 32768;
        int j = t2 & 7, l = (t2 >> 3) & 63, f = t2 >> 9;
        int ks = f & 7, nt = f >> 3;
        int k = ks * 32 + ((l >> 4) << 3) + j, n = nt * 16 + (l & 15);
        w2f[t2] = (u16)f2bf_bits(mw2[(size_t)k * C_DIM + n]);
    } else if (t < 65536 + 4096) {  // w3f: [nt8][64][8], W = kw3 [32][128]
        int t3 = t - 65536;
        int j = t3 & 7, l = (t3 >> 3) & 63, nt = t3 >> 9;
        int k = ((l >> 4) << 3) + j, n = nt * 16 + (l & 15);
        w3f[t3] = (u16)f2bf_bits(kw3[(size_t)k * C_DIM + n]);
    }
}

// ---------- conv (MFMA): W=k2@w3+b3 on matrix cores, gather h, fused LN2+mod ----------
__global__ __launch_bounds__(256) void k_conv3(
        const float* __restrict__ feats,
        const float* __restrict__ h_mod,      // (N+1) rows, row N = zeros
        const float* __restrict__ normv,
        const int* __restrict__ start,
        const int* __restrict__ src_sorted,
        const u16* __restrict__ k2h,          // [E][32] bf16 (sorted order)
        const u16* __restrict__ w3f,          // frag-major
        const float* __restrict__ b3,
        const float* __restrict__ cbias,
        const float* __restrict__ tm2,
        const float* __restrict__ ln2s, const float* __restrict__ ln2b,
        float* __restrict__ xio,              // out: x = feats + conv (d_out)
        u16* __restrict__ xmb,                // out: modulate2(x) bf16
        int N, int q) {
    int l  = threadIdx.x & 63;
    int n  = blockIdx.x * 4 + (threadIdx.x >> 6);
    int lr = l & 15, g = l >> 4;

    bf16x8 wb[8];
#pragma unroll
    for (int nt = 0; nt < 8; ++nt)
        wb[nt] = *(const bf16x8*)(w3f + ((size_t)nt * 64 + l) * 8);
    f32x4 binit[8];
#pragma unroll
    for (int nt = 0; nt < 8; ++nt) {
        float bv = b3[nt * 16 + lr];
        binit[nt][0] = bv; binit[nt][1] = bv; binit[nt][2] = bv; binit[nt][3] = bv;
    }

    int s = start[n], e = start[n + 1];
    float acc[8] = {0.f, 0.f, 0.f, 0.f, 0.f, 0.f, 0.f, 0.f};

    for (int p0 = s; p0 < e; p0 += 16) {
        int pa = p0 + lr;
        bf16x8 a = {0, 0, 0, 0, 0, 0, 0, 0};
        if (pa < e) a = *(const bf16x8*)(k2h + (size_t)pa * FC + g * 8);
        int srcv[4];
#pragma unroll
        for (int r = 0; r < 4; ++r) {
            int pp = p0 + 4 * g + r;
            srcv[r] = (pp < e) ? src_sorted[pp] : N;   // row N of h_mod = zeros
        }
#pragma unroll
        for (int nt = 0; nt < 8; ++nt) {
            f32x4 w = __builtin_amdgcn_mfma_f32_16x16x32_bf16(a, wb[nt], binit[nt], 0, 0, 0);
#pragma unroll
            for (int r = 0; r < 4; ++r)
                acc[nt] += w[r] * h_mod[(size_t)srcv[r] * C_DIM + nt * 16 + lr];
        }
    }
#pragma unroll
    for (int nt = 0; nt < 8; ++nt) {
        acc[nt] += __shfl_xor(acc[nt], 16, 64);
        acc[nt] += __shfl_xor(acc[nt], 32, 64);
    }

    float rnv = fast_rcp(normv[n]);
    float xv[8], m1 = 0.f, m2 = 0.f;
#pragma unroll
    for (int nt = 0; nt < 8; ++nt) {
        int c = nt * 16 + lr;
        float v = feats[(size_t)n * C_DIM + c] + (acc[nt] + cbias[c]) * rnv;
        xv[nt] = v; m1 += v; m2 += v * v;
    }
#pragma unroll
    for (int off = 1; off <= 8; off <<= 1) {
        m1 += __shfl_xor(m1, off, 64);
        m2 += __shfl_xor(m2, off, 64);
    }
    float mean = m1 * (1.0f / C_DIM);
    float rstd = rsqrtf(m2 * (1.0f / C_DIM) - mean * mean + 1e-5f);
    int b = n / q;
    bool wr = (g == 0);
#pragma unroll
    for (int nt = 0; nt < 8; ++nt) {
        int c = nt * 16 + lr;
        size_t o = (size_t)n * C_DIM + c;
        float sc = tm2[(size_t)b * TWO_C + c];
        float sh = tm2[(size_t)b * TWO_C + C_DIM + c];
        float h2 = ((xv[nt] - mean) * rstd * ln2s[c] + ln2b[c]) * (1.0f + sc) + sh;
        if (wr) { xio[o] = xv[nt]; xmb[o] = (u16)f2bf_bits(h2); }
    }
}

// ---------- FFN (MFMA): out += gelu(xm@w1+b1)@w2+b2 ; per-wave 16 rows ----------
__global__ __launch_bounds__(256) void k_ffn2(const u16* __restrict__ xm,
                                              const u16* __restrict__ w1f,
                                              const float* __restrict__ b1,
                                              const u16* __restrict__ w2f,
                                              const float* __restrict__ b2,
                                              float* __restrict__ xio, int N) {
    __shared__ u16 sm[4][4096];                 // per-wave m tile [16][256] bf16
    int tid = threadIdx.x, w = tid >> 6, l = tid & 63;
    int lr = l & 15, g = l >> 4;
    int n0 = blockIdx.x * 64 + w * 16;
    u16* smw = sm[w];

    bf16x8 a[4];
    const u16* xrow = xm + (size_t)(n0 + lr) * C_DIM;
#pragma unroll
    for (int ks = 0; ks < 4; ++ks)
        a[ks] = *(const bf16x8*)(xrow + ks * 32 + g * 8);
    f32x4 acc[16];
#pragma unroll
    for (int nt = 0; nt < 16; ++nt) {
        float bv = b1[nt * 16 + lr];
        acc[nt][0] = bv; acc[nt][1] = bv; acc[nt][2] = bv; acc[nt][3] = bv;
    }
#pragma unroll
    for (int nt = 0; nt < 16; ++nt)
#pragma unroll
        for (int ks = 0; ks < 4; ++ks) {
            bf16x8 bfr = *(const bf16x8*)(w1f + ((size_t)(nt * 4 + ks) * 64 + l) * 8);
            acc[nt] = __builtin_amdgcn_mfma_f32_16x16x32_bf16(a[ks], bfr, acc[nt], 0, 0, 0);
        }
#pragma unroll
    for (int nt = 0; nt < 16; ++nt)
#pragma unroll
        for (int r = 0; r < 4; ++r) {
            int row = 4 * g + r, col = nt * 16 + lr;
            int byte = row * 512 + ((col * 2) ^ ((row & 7) << 4));
            smw[byte >> 1] = (u16)f2bf_bits(gelu_f(acc[nt][r]));
        }
    f32x4 acc2[8];
#pragma unroll
    for (int nt = 0; nt < 8; ++nt) {
        float bv = b2[nt * 16 + lr];
        acc2[nt][0] = bv; acc2[nt][1] = bv; acc2[nt][2] = bv; acc2[nt][3] = bv;
    }
#pragma unroll
    for (int ks = 0; ks < 8; ++ks) {
        int byte = lr * 512 + ((ks * 64 + g * 16) ^ ((lr & 7) << 4));
        bf16x8 a2 = *(const bf16x8*)(smw + (byte >> 1));
#pragma unroll
        for (int nt = 0; nt < 8; ++nt) {
            bf16x8 bfr = *(const bf16x8*)(w2f + ((size_t)(nt * 8 + ks) * 64 + l) * 8);
            acc2[nt] = __builtin_amdgcn_mfma_f32_16x16x32_bf16(a2, bfr, acc2[nt], 0, 0, 0);
        }
    }
#pragma unroll
    for (int nt = 0; nt < 8; ++nt)
#pragma unroll
        for (int r = 0; r < 4; ++r) {
            size_t o = (size_t)(n0 + 4 * g + r) * C_DIM + nt * 16 + lr;
            xio[o] += acc2[nt][r];
        }
}

// ---------- atomic fallback ----------
__global__ __launch_bounds__(256) void k_edge_atomic(
        const int* __restrict__ ei, const float* __restrict__ ea,
        const float* __restrict__ w1, const float* __restrict__ b1,
        const float* __restrict__ w2, const float* __restrict__ b2,
        const float* __restrict__ w3, const float* __restrict__ b3,
        const float* __restrict__ h_mod, float* __restrict__ xacc, int E) {
    int e = blockIdx.x * 256 + threadIdx.x;
    if (e >= E) return;
    int src = ei[e], dst = ei[E + e];
    float ax = ea[(size_t)e * 2], ay = ea[(size_t)e * 2 + 1];
    float k1[FC];
#pragma unroll
    for (int i = 0; i < FC; ++i) k1[i] = gelu_f(ax * w1[i] + ay * w1[FC + i] + b1[i]);
    float k2v[FC];
#pragma unroll
    for (int j = 0; j < FC; ++j) {
        float acc = b2[j];
#pragma unroll
        for (int i = 0; i < FC; ++i) acc += k1[i] * w2[i * FC + j];
        k2v[j] = gelu_f(acc);
    }
    const float* hrow = h_mod + (size_t)src * C_DIM;
    float* orow = xacc + (size_t)dst * C_DIM;
    for (int c = 0; c < C_DIM; ++c) {
        float wv = b3[c];
#pragma unroll
        for (int j = 0; j < FC; ++j) wv += k2v[j] * w3[j * C_DIM + c];
        atomicAdd(&orow[c], wv * hrow[c]);
    }
}

__global__ void k_finish(const float* __restrict__ feats, const float* __restrict__ cbias,
                         const float* __restrict__ normv, float* __restrict__ xbuf, int NC) {
    int i = blockIdx.x * 256 + threadIdx.x;
    if (i >= NC) return;
    int c = i & (C_DIM - 1);
    int n = i >> 7;
    xbuf[i] = feats[i] + (xbuf[i] + cbias[c]) / normv[n];
}

extern "C" void kernel_launch(void* const* d_in, const int* in_sizes, int n_in,
                              void* d_out, int out_size, void* d_ws, size_t ws_size,
                              hipStream_t stream) {
    const float* feats = (const float*)d_in[0];
    const int*   ei    = (const int*)d_in[1];
    const float* ea    = (const float*)d_in[2];
    const float* t     = (const float*)d_in[3];
    const float* normv = (const float*)d_in[4];
    const float* ln1s  = (const float*)d_in[5];
    const float* ln1b  = (const float*)d_in[6];
    const float* ln2s  = (const float*)d_in[7];
    const float* ln2b  = (const float*)d_in[8];
    const float* tw1   = (const float*)d_in[9];
    const float* tb1   = (const float*)d_in[10];
    const float* tw2   = (const float*)d_in[11];
    const float* tb2   = (const float*)d_in[12];
    const float* kw1   = (const float*)d_in[13];
    const float* kb1   = (const float*)d_in[14];
    const float* kw2   = (const float*)d_in[15];
    const float* kb2   = (const float*)d_in[16];
    const float* kw3   = (const float*)d_in[17];
    const float* kb3   = (const float*)d_in[18];
    const float* cbias = (const float*)d_in[19];
    const float* mw1   = (const float*)d_in[20];
    const float* mb1   = (const float*)d_in[21];
    const float* mw2   = (const float*)d_in[22];
    const float* mb2   = (const float*)d_in[23];
    float* out = (float*)d_out;

    const int N = in_sizes[0] / C_DIM;
    const int E = in_sizes[1] / 2;
    const int B = in_sizes[3] / T_DIM;
    const int q = N / B;

    char* wp = (char*)d_ws;
    auto alloc = [&](size_t bytes) -> char* {
        char* p = wp; wp += (bytes + 255) & ~(size_t)255; return p;
    };
    float* tm1        = (float*)alloc((size_t)B * TWO_C * 4);
    float* tm2        = (float*)alloc((size_t)B * TWO_C * 4);
    float* h_mod      = (float*)alloc(((size_t)N + 1) * C_DIM * 4);  // +1 zero row
    u16*   xmb        = (u16*)alloc((size_t)N * C_DIM * 2);
    u16*   w1f        = (u16*)alloc((size_t)C_DIM * TWO_C * 2);
    u16*   w2f        = (u16*)alloc((size_t)TWO_C * C_DIM * 2);
    u16*   w3f        = (u16*)alloc((size_t)FC * C_DIM * 2);
    int*   cnt        = (int*)alloc(((size_t)N + 1) * 4);
    int*   cursor     = (int*)alloc((size_t)N * 4);
    int*   rank       = (int*)alloc((size_t)E * 4);
    int*   src_sorted = (int*)alloc((size_t)E * 4);
    size_t fixed = (size_t)(wp - (char*)d_ws);
    bool can_sort = ws_size >= fixed + ((size_t)E + 16) * FC * 2;
    u16* k2h = (u16*)alloc(((size_t)E + 16) * FC * 2);

    const int eb = (E + 255) / 256;

    k_tmod<<<dim3(B, 2), 256, 0, stream>>>(t, tw1, tb1, tm1, tw2, tb2, tm2);
    k_mod<false><<<N, C_DIM, 0, stream>>>(feats, ln1s, ln1b, tm1, h_mod, q);
    k_prep<<<(65536 + 4096 + 255) / 256, 256, 0, stream>>>(mw1, mw2, kw3, w1f, w2f, w3f);
    hipMemsetAsync(h_mod + (size_t)N * C_DIM, 0, C_DIM * 4, stream);  // zero row N

    if (can_sort) {
        hipMemsetAsync(cnt, 0, ((size_t)N + 1) * 4, stream);
        k_hist<<<eb, 256, 0, stream>>>(ei + E, cnt, E);
        k_scan<<<1, 1024, 0, stream>>>(cnt, cursor, N);
        k_scatter<<<eb, 256, 0, stream>>>(ei, cursor, rank, src_sorted, E);
        k_edgek2<<<eb, 256, 0, stream>>>(rank, ea, kw1, kb1, kw2, kb2, k2h, E);
        k_conv3<<<N / 4, 256, 0, stream>>>(feats, h_mod, normv, cnt, src_sorted,
                                           k2h, w3f, kb3, cbias, tm2, ln2s, ln2b,
                                           out, xmb, N, q);
    } else {
        hipMemsetAsync(out, 0, (size_t)N * C_DIM * 4, stream);
        k_edge_atomic<<<eb, 256, 0, stream>>>(ei, ea, kw1, kb1, kw2, kb2, kw3, kb3,
                                              h_mod, out, E);
        int nc = N * C_DIM;
        k_finish<<<(nc + 255) / 256, 256, 0, stream>>>(feats, cbias, normv, out, nc);
        k_mod<true><<<N, C_DIM, 0, stream>>>(out, ln2s, ln2b, tm2, xmb, q);
    }

    k_ffn2<<<N / 64, 256, 0, stream>>>(xmb, w1f, mb1, w2f, mb2, out, N);
}

// Round 4
// 399.439 us; speedup vs baseline: 2.7014x; 1.1239x over previous
//
#include <hip/hip_runtime.h>
#include <hip/hip_bf16.h>

#define C_DIM 128
#define TWO_C 256
#define FC    32
#define T_DIM 512

typedef unsigned int   u32;
typedef unsigned short u16;
typedef short bf16x8 __attribute__((ext_vector_type(8)));
typedef float f32x4  __attribute__((ext_vector_type(4)));

__device__ __forceinline__ float fast_rcp(float x) {
    return __builtin_amdgcn_rcpf(x);          // v_rcp_f32, ~1 ULP
}
// gelu via A&S 7.1.27 rational erf (|eps_erf| <= 5e-4), 1/sqrt2 folded into coeffs.
// erf(|x|/sqrt2) = 1 - 1/p^4,  p = 1 + b1|x| + b2 x^2 + b3 |x|^3 + b4 x^4
__device__ __forceinline__ float gelu_f(float x) {
    float a = fabsf(x);
    float p = 1.0f + a * (0.19685352f + a * (0.11519450f +
              a * (3.4364302e-4f + a * 0.019527027f)));
    float d  = fast_rcp(p);
    float d2 = d * d;
    float d4 = d2 * d2;
    float s = 0.5f * x;
    return s + s * copysignf(1.0f - d4, x);
}
__device__ __forceinline__ u32 f2bf_bits(float x) {
    u32 u = __float_as_uint(x);
    return (u + 0x7fffu + ((u >> 16) & 1u)) >> 16;   // RNE f32->bf16
}
__device__ __forceinline__ float bf2f(u16 v) {
    return __uint_as_float((u32)v << 16);
}

// ---------- time modulation: tm = gelu(t) @ tw + tb, both mlps in one grid ----------
__global__ __launch_bounds__(256) void k_tmod(const float* __restrict__ t,
                                              const float* __restrict__ tw1,
                                              const float* __restrict__ tb1,
                                              float* __restrict__ tm1,
                                              const float* __restrict__ tw2,
                                              const float* __restrict__ tb2,
                                              float* __restrict__ tm2) {
    const float* tw = blockIdx.y ? tw2 : tw1;
    const float* tb = blockIdx.y ? tb2 : tb1;
    float*       tm = blockIdx.y ? tm2 : tm1;
    __shared__ float gt[T_DIM];
    int b = blockIdx.x;
    for (int k = threadIdx.x; k < T_DIM; k += 256)
        gt[k] = gelu_f(t[(size_t)b * T_DIM + k]);
    __syncthreads();
    int j = threadIdx.x;
    float acc = tb[j];
    for (int k = 0; k < T_DIM; ++k)
        acc += gt[k] * tw[(size_t)k * TWO_C + j];
    tm[(size_t)b * TWO_C + j] = acc;
}

// ---------- modulate: out = LN(in)*(1+scale) + shift ----------
template <bool BF16OUT>
__global__ __launch_bounds__(C_DIM) void k_mod(const float* __restrict__ in,
                                               const float* __restrict__ lns,
                                               const float* __restrict__ lnb,
                                               const float* __restrict__ tm,
                                               void* __restrict__ outp, int q) {
    int n = blockIdx.x, c = threadIdx.x;
    size_t o = (size_t)n * C_DIM + c;
    float v = in[o];
    float s1 = v, s2 = v * v;
#pragma unroll
    for (int off = 32; off > 0; off >>= 1) {
        s1 += __shfl_down(s1, off);
        s2 += __shfl_down(s2, off);
    }
    __shared__ float red[4];
    if ((c & 63) == 0) { red[(c >> 6) * 2] = s1; red[(c >> 6) * 2 + 1] = s2; }
    __syncthreads();
    float mean = (red[0] + red[2]) * (1.0f / C_DIM);
    float ex2  = (red[1] + red[3]) * (1.0f / C_DIM);
    float r    = rsqrtf(ex2 - mean * mean + 1e-5f);
    int b = n / q;
    float scale = tm[(size_t)b * TWO_C + c];
    float shift = tm[(size_t)b * TWO_C + C_DIM + c];
    float h = (v - mean) * r * lns[c] + lnb[c];
    float res = h * (1.0f + scale) + shift;
    if (BF16OUT) ((u16*)outp)[o] = (u16)f2bf_bits(res);
    else         ((float*)outp)[o] = res;
}

// ---------- counting sort by dst ----------
__global__ void k_hist(const int* __restrict__ dst, int* __restrict__ cnt, int E) {
    int e = blockIdx.x * 256 + threadIdx.x;
    if (e < E) atomicAdd(&cnt[dst[e]], 1);
}

__global__ __launch_bounds__(1024) void k_scan(int* __restrict__ data,
                                               int* __restrict__ cursor, int N) {
    __shared__ int tot[1024];
    int t = threadIdx.x;
    const int PER = 32;
    int base = t * PER;
    int loc[PER];
    int s = 0;
#pragma unroll
    for (int i = 0; i < PER; ++i) {
        int idx = base + i;
        int v = (idx < N) ? data[idx] : 0;
        loc[i] = s; s += v;
    }
    tot[t] = s;
    __syncthreads();
    for (int off = 1; off < 1024; off <<= 1) {
        int v = (t >= off) ? tot[t - off] : 0;
        __syncthreads();
        tot[t] += v;
        __syncthreads();
    }
    int bb = (t == 0) ? 0 : tot[t - 1];
#pragma unroll
    for (int i = 0; i < PER; ++i) {
        int idx = base + i;
        if (idx < N) { int v = bb + loc[i]; data[idx] = v; cursor[idx] = v; }
    }
    if (t == 1023) data[N] = tot[1023];
}

// rank[e] = position of edge e in dst-sorted order; also write src_sorted directly
__global__ void k_scatter(const int* __restrict__ ei, int* __restrict__ cursor,
                          int* __restrict__ rank, int* __restrict__ src_sorted, int E) {
    int e = blockIdx.x * 256 + threadIdx.x;
    if (e < E) {
        int pos = atomicAdd(&cursor[ei[E + e]], 1);
        rank[e] = pos;
        src_sorted[pos] = ei[e];
    }
}

// ---------- edge kernel-MLP: k1 in-fragment (VALU) + layer2 on MFMA ----------
// k2 row stored permuted: u32 slot m = (dim m, dim m+16); w3f prep matches (pi).
__global__ __launch_bounds__(256) void k_edgek2(
        const int* __restrict__ rank,
        const float* __restrict__ ea,
        const float* __restrict__ w1, const float* __restrict__ b1,
        const u16* __restrict__ w2kf, const float* __restrict__ b2,
        u32* __restrict__ k2w, int E) {
    int l = threadIdx.x & 63, wv = threadIdx.x >> 6;
    int lr = l & 15, g = l >> 4;
    int wbase = blockIdx.x * 256 + wv * 64;

    bf16x8 wb0 = *(const bf16x8*)(w2kf + (size_t)l * 8);
    bf16x8 wb1 = *(const bf16x8*)(w2kf + (size_t)(64 + l) * 8);
    f32x4 bi0, bi1;
    {
        float v0 = b2[lr], v1 = b2[16 + lr];
        bi0[0] = v0; bi0[1] = v0; bi0[2] = v0; bi0[3] = v0;
        bi1[0] = v1; bi1[1] = v1; bi1[2] = v1; bi1[3] = v1;
    }
    float w1x[8], w1y[8], b1v[8];
#pragma unroll
    for (int j = 0; j < 8; ++j) {
        w1x[j] = w1[8 * g + j];
        w1y[j] = w1[FC + 8 * g + j];
        b1v[j] = b1[8 * g + j];
    }
#pragma unroll
    for (int c = 0; c < 4; ++c) {
        int cb = wbase + 16 * c;
        int eA = cb + lr;                      // A row lr = edge cb+lr
        float2 av = make_float2(0.f, 0.f);
        if (eA < E) av = ((const float2*)ea)[eA];
        union { u32 w[4]; bf16x8 v; } au;
#pragma unroll
        for (int m = 0; m < 4; ++m) {
            float v0 = gelu_f(av.x * w1x[2 * m]     + av.y * w1y[2 * m]     + b1v[2 * m]);
            float v1 = gelu_f(av.x * w1x[2 * m + 1] + av.y * w1y[2 * m + 1] + b1v[2 * m + 1]);
            au.w[m] = f2bf_bits(v0) | (f2bf_bits(v1) << 16);
        }
        f32x4 d0 = __builtin_amdgcn_mfma_f32_16x16x32_bf16(au.v, wb0, bi0, 0, 0, 0);
        f32x4 d1 = __builtin_amdgcn_mfma_f32_16x16x32_bf16(au.v, wb1, bi1, 0, 0, 0);
#pragma unroll
        for (int r = 0; r < 4; ++r) {
            int eD = cb + 4 * g + r;           // D row 4g+r = edge cb+4g+r
            if (eD < E) {
                u32 pk = f2bf_bits(gelu_f(d0[r])) | (f2bf_bits(gelu_f(d1[r])) << 16);
                k2w[(size_t)rank[eD] * 16 + lr] = pk;   // 16 lanes = 64B segment
            }
        }
    }
}

// ---------- prep: frag-major bf16 layouts ----------
// w1f/w2f (FFN): natural k. w3f: k permuted by pi(kk)=(kk>>1)+((kk&1)<<4) to match
// k2 row storage. w2kf (edge layer2): natural k, [nt2][64][8].
#define PREP_TOT (32768 + 32768 + 4096 + 1024)
__global__ __launch_bounds__(256) void k_prep(const float* __restrict__ mw1,
                                              const float* __restrict__ mw2,
                                              const float* __restrict__ kw3,
                                              const float* __restrict__ kw2,
                                              u16* __restrict__ w1f,
                                              u16* __restrict__ w2f,
                                              u16* __restrict__ w3f,
                                              u16* __restrict__ w2kf) {
    int t = blockIdx.x * 256 + threadIdx.x;
    if (t < 32768) {            // w1f: [nt16][ks4][64][8], W = mw1 [128][256]
        int j = t & 7, l = (t >> 3) & 63, f = t >> 9;
        int ks = f & 3, nt = f >> 2;
        int k = ks * 32 + ((l >> 4) << 3) + j, n = nt * 16 + (l & 15);
        w1f[t] = (u16)f2bf_bits(mw1[(size_t)k * TWO_C + n]);
    } else if (t < 65536) {     // w2f: [nt8][ks8][64][8], W = mw2 [256][128]
        int t2 = t - 32768;
        int j = t2 & 7, l = (t2 >> 3) & 63, f = t2 >> 9;
        int ks = f & 7, nt = f >> 3;
        int k = ks * 32 + ((l >> 4) << 3) + j, n = nt * 16 + (l & 15);
        w2f[t2] = (u16)f2bf_bits(mw2[(size_t)k * C_DIM + n]);
    } else if (t < 69632) {     // w3f: [nt8][64][8], W = kw3 [32][128], k permuted
        int t3 = t - 65536;
        int j = t3 & 7, l = (t3 >> 3) & 63, nt = t3 >> 9;
        int kk = ((l >> 4) << 3) + j;
        int k = (kk >> 1) + ((kk & 1) << 4);
        int n = nt * 16 + (l & 15);
        w3f[t3] = (u16)f2bf_bits(kw3[(size_t)k * C_DIM + n]);
    } else if (t < PREP_TOT) {  // w2kf: [nt2][64][8], W = kw2 [32][32], natural k
        int t4 = t - 69632;
        int j = t4 & 7, l = (t4 >> 3) & 63, nt = t4 >> 9;
        int kk = ((l >> 4) << 3) + j;
        int n = nt * 16 + (l & 15);
        w2kf[t4] = (u16)f2bf_bits(kw2[(size_t)kk * FC + n]);
    }
}

// ---------- conv (MFMA): W=k2@w3+b3, gather bf16 h, fused LN2+mod ----------
__global__ __launch_bounds__(256) void k_conv3(
        const float* __restrict__ feats,
        const u16* __restrict__ h_mod,        // (N+1) rows bf16, row N = zeros
        const float* __restrict__ normv,
        const int* __restrict__ start,
        const int* __restrict__ src_sorted,
        const u16* __restrict__ k2h,          // [E][32] bf16 (sorted, permuted rows)
        const u16* __restrict__ w3f,          // frag-major, matching permutation
        const float* __restrict__ b3,
        const float* __restrict__ cbias,
        const float* __restrict__ tm2,
        const float* __restrict__ ln2s, const float* __restrict__ ln2b,
        float* __restrict__ xio,              // out: x = feats + conv (d_out)
        u16* __restrict__ xmb,                // out: modulate2(x) bf16
        int N, int q) {
    int l  = threadIdx.x & 63;
    int n  = blockIdx.x * 4 + (threadIdx.x >> 6);
    int lr = l & 15, g = l >> 4;

    bf16x8 wb[8];
#pragma unroll
    for (int nt = 0; nt < 8; ++nt)
        wb[nt] = *(const bf16x8*)(w3f + ((size_t)nt * 64 + l) * 8);
    f32x4 binit[8];
#pragma unroll
    for (int nt = 0; nt < 8; ++nt) {
        float bv = b3[nt * 16 + lr];
        binit[nt][0] = bv; binit[nt][1] = bv; binit[nt][2] = bv; binit[nt][3] = bv;
    }

    int s = start[n], e = start[n + 1];
    float acc[8] = {0.f, 0.f, 0.f, 0.f, 0.f, 0.f, 0.f, 0.f};

    for (int p0 = s; p0 < e; p0 += 16) {
        int pa = p0 + lr;
        bf16x8 a = {0, 0, 0, 0, 0, 0, 0, 0};
        if (pa < e) a = *(const bf16x8*)(k2h + (size_t)pa * FC + g * 8);
        int srcv[4];
#pragma unroll
        for (int r = 0; r < 4; ++r) {
            int pp = p0 + 4 * g + r;
            srcv[r] = (pp < e) ? src_sorted[pp] : N;   // row N of h_mod = zeros
        }
#pragma unroll
        for (int nt = 0; nt < 8; ++nt) {
            f32x4 w = __builtin_amdgcn_mfma_f32_16x16x32_bf16(a, wb[nt], binit[nt], 0, 0, 0);
#pragma unroll
            for (int r = 0; r < 4; ++r)
                acc[nt] += w[r] * bf2f(h_mod[(size_t)srcv[r] * C_DIM + nt * 16 + lr]);
        }
    }
#pragma unroll
    for (int nt = 0; nt < 8; ++nt) {
        acc[nt] += __shfl_xor(acc[nt], 16, 64);
        acc[nt] += __shfl_xor(acc[nt], 32, 64);
    }

    float rnv = fast_rcp(normv[n]);
    float xv[8], m1 = 0.f, m2 = 0.f;
#pragma unroll
    for (int nt = 0; nt < 8; ++nt) {
        int c = nt * 16 + lr;
        float v = feats[(size_t)n * C_DIM + c] + (acc[nt] + cbias[c]) * rnv;
        xv[nt] = v; m1 += v; m2 += v * v;
    }
#pragma unroll
    for (int off = 1; off <= 8; off <<= 1) {
        m1 += __shfl_xor(m1, off, 64);
        m2 += __shfl_xor(m2, off, 64);
    }
    float mean = m1 * (1.0f / C_DIM);
    float rstd = rsqrtf(m2 * (1.0f / C_DIM) - mean * mean + 1e-5f);
    int b = n / q;
    bool wr = (g == 0);
#pragma unroll
    for (int nt = 0; nt < 8; ++nt) {
        int c = nt * 16 + lr;
        size_t o = (size_t)n * C_DIM + c;
        float sc = tm2[(size_t)b * TWO_C + c];
        float sh = tm2[(size_t)b * TWO_C + C_DIM + c];
        float h2 = ((xv[nt] - mean) * rstd * ln2s[c] + ln2b[c]) * (1.0f + sc) + sh;
        if (wr) { xio[o] = xv[nt]; xmb[o] = (u16)f2bf_bits(h2); }
    }
}

// ---------- FFN (MFMA): out += gelu(xm@w1+b1)@w2+b2 ; per-wave 16 rows ----------
__global__ __launch_bounds__(256) void k_ffn2(const u16* __restrict__ xm,
                                              const u16* __restrict__ w1f,
                                              const float* __restrict__ b1,
                                              const u16* __restrict__ w2f,
                                              const float* __restrict__ b2,
                                              float* __restrict__ xio, int N) {
    __shared__ u16 sm[4][4096];                 // per-wave m tile [16][256] bf16
    int tid = threadIdx.x, w = tid >> 6, l = tid & 63;
    int lr = l & 15, g = l >> 4;
    int n0 = blockIdx.x * 64 + w * 16;
    u16* smw = sm[w];

    bf16x8 a[4];
    const u16* xrow = xm + (size_t)(n0 + lr) * C_DIM;
#pragma unroll
    for (int ks = 0; ks < 4; ++ks)
        a[ks] = *(const bf16x8*)(xrow + ks * 32 + g * 8);
    f32x4 acc[16];
#pragma unroll
    for (int nt = 0; nt < 16; ++nt) {
        float bv = b1[nt * 16 + lr];
        acc[nt][0] = bv; acc[nt][1] = bv; acc[nt][2] = bv; acc[nt][3] = bv;
    }
#pragma unroll
    for (int nt = 0; nt < 16; ++nt)
#pragma unroll
        for (int ks = 0; ks < 4; ++ks) {
            bf16x8 bfr = *(const bf16x8*)(w1f + ((size_t)(nt * 4 + ks) * 64 + l) * 8);
            acc[nt] = __builtin_amdgcn_mfma_f32_16x16x32_bf16(a[ks], bfr, acc[nt], 0, 0, 0);
        }
#pragma unroll
    for (int nt = 0; nt < 16; ++nt)
#pragma unroll
        for (int r = 0; r < 4; ++r) {
            int row = 4 * g + r, col = nt * 16 + lr;
            int byte = row * 512 + ((col * 2) ^ ((row & 7) << 4));
            smw[byte >> 1] = (u16)f2bf_bits(gelu_f(acc[nt][r]));
        }
    f32x4 acc2[8];
#pragma unroll
    for (int nt = 0; nt < 8; ++nt) {
        float bv = b2[nt * 16 + lr];
        acc2[nt][0] = bv; acc2[nt][1] = bv; acc2[nt][2] = bv; acc2[nt][3] = bv;
    }
#pragma unroll
    for (int ks = 0; ks < 8; ++ks) {
        int byte = lr * 512 + ((ks * 64 + g * 16) ^ ((lr & 7) << 4));
        bf16x8 a2 = *(const bf16x8*)(smw + (byte >> 1));
#pragma unroll
        for (int nt = 0; nt < 8; ++nt) {
            bf16x8 bfr = *(const bf16x8*)(w2f + ((size_t)(nt * 8 + ks) * 64 + l) * 8);
            acc2[nt] = __builtin_amdgcn_mfma_f32_16x16x32_bf16(a2, bfr, acc2[nt], 0, 0, 0);
        }
    }
#pragma unroll
    for (int nt = 0; nt < 8; ++nt)
#pragma unroll
        for (int r = 0; r < 4; ++r) {
            size_t o = (size_t)(n0 + 4 * g + r) * C_DIM + nt * 16 + lr;
            xio[o] += acc2[nt][r];
        }
}

// ---------- atomic fallback ----------
__global__ __launch_bounds__(256) void k_edge_atomic(
        const int* __restrict__ ei, const float* __restrict__ ea,
        const float* __restrict__ w1, const float* __restrict__ b1,
        const float* __restrict__ w2, const float* __restrict__ b2,
        const float* __restrict__ w3, const float* __restrict__ b3,
        const u16* __restrict__ h_mod, float* __restrict__ xacc, int E) {
    int e = blockIdx.x * 256 + threadIdx.x;
    if (e >= E) return;
    int src = ei[e], dst = ei[E + e];
    float ax = ea[(size_t)e * 2], ay = ea[(size_t)e * 2 + 1];
    float k1[FC];
#pragma unroll
    for (int i = 0; i < FC; ++i) k1[i] = gelu_f(ax * w1[i] + ay * w1[FC + i] + b1[i]);
    float k2v[FC];
#pragma unroll
    for (int j = 0; j < FC; ++j) {
        float acc = b2[j];
#pragma unroll
        for (int i = 0; i < FC; ++i) acc += k1[i] * w2[i * FC + j];
        k2v[j] = gelu_f(acc);
    }
    const u16* hrow = h_mod + (size_t)src * C_DIM;
    float* orow = xacc + (size_t)dst * C_DIM;
    for (int c = 0; c < C_DIM; ++c) {
        float wv = b3[c];
#pragma unroll
        for (int j = 0; j < FC; ++j) wv += k2v[j] * w3[j * C_DIM + c];
        atomicAdd(&orow[c], wv * bf2f(hrow[c]));
    }
}

__global__ void k_finish(const float* __restrict__ feats, const float* __restrict__ cbias,
                         const float* __restrict__ normv, float* __restrict__ xbuf, int NC) {
    int i = blockIdx.x * 256 + threadIdx.x;
    if (i >= NC) return;
    int c = i & (C_DIM - 1);
    int n = i >> 7;
    xbuf[i] = feats[i] + (xbuf[i] + cbias[c]) / normv[n];
}

extern "C" void kernel_launch(void* const* d_in, const int* in_sizes, int n_in,
                              void* d_out, int out_size, void* d_ws, size_t ws_size,
                              hipStream_t stream) {
    const float* feats = (const float*)d_in[0];
    const int*   ei    = (const int*)d_in[1];
    const float* ea    = (const float*)d_in[2];
    const float* t     = (const float*)d_in[3];
    const float* normv = (const float*)d_in[4];
    const float* ln1s  = (const float*)d_in[5];
    const float* ln1b  = (const float*)d_in[6];
    const float* ln2s  = (const float*)d_in[7];
    const float* ln2b  = (const float*)d_in[8];
    const float* tw1   = (const float*)d_in[9];
    const float* tb1   = (const float*)d_in[10];
    const float* tw2   = (const float*)d_in[11];
    const float* tb2   = (const float*)d_in[12];
    const float* kw1   = (const float*)d_in[13];
    const float* kb1   = (const float*)d_in[14];
    const float* kw2   = (const float*)d_in[15];
    const float* kb2   = (const float*)d_in[16];
    const float* kw3   = (const float*)d_in[17];
    const float* kb3   = (const float*)d_in[18];
    const float* cbias = (const float*)d_in[19];
    const float* mw1   = (const float*)d_in[20];
    const float* mb1   = (const float*)d_in[21];
    const float* mw2   = (const float*)d_in[22];
    const float* mb2   = (const float*)d_in[23];
    float* out = (float*)d_out;

    const int N = in_sizes[0] / C_DIM;
    const int E = in_sizes[1] / 2;
    const int B = in_sizes[3] / T_DIM;
    const int q = N / B;

    char* wp = (char*)d_ws;
    auto alloc = [&](size_t bytes) -> char* {
        char* p = wp; wp += (bytes + 255) & ~(size_t)255; return p;
    };
    float* tm1        = (float*)alloc((size_t)B * TWO_C * 4);
    float* tm2        = (float*)alloc((size_t)B * TWO_C * 4);
    u16*   h_mod      = (u16*)alloc(((size_t)N + 1) * C_DIM * 2);   // bf16, +1 zero row
    u16*   xmb        = (u16*)alloc((size_t)N * C_DIM * 2);
    u16*   w1f        = (u16*)alloc((size_t)C_DIM * TWO_C * 2);
    u16*   w2f        = (u16*)alloc((size_t)TWO_C * C_DIM * 2);
    u16*   w3f        = (u16*)alloc((size_t)FC * C_DIM * 2);
    u16*   w2kf       = (u16*)alloc((size_t)FC * FC * 2);
    int*   cnt        = (int*)alloc(((size_t)N + 1) * 4);
    int*   cursor     = (int*)alloc((size_t)N * 4);
    int*   rank       = (int*)alloc((size_t)E * 4);
    int*   src_sorted = (int*)alloc((size_t)E * 4);
    size_t fixed = (size_t)(wp - (char*)d_ws);
    bool can_sort = ws_size >= fixed + ((size_t)E + 16) * FC * 2;
    u16* k2h = (u16*)alloc(((size_t)E + 16) * FC * 2);

    const int eb = (E + 255) / 256;

    k_tmod<<<dim3(B, 2), 256, 0, stream>>>(t, tw1, tb1, tm1, tw2, tb2, tm2);
    k_mod<true><<<N, C_DIM, 0, stream>>>(feats, ln1s, ln1b, tm1, h_mod, q);
    k_prep<<<(PREP_TOT + 255) / 256, 256, 0, stream>>>(mw1, mw2, kw3, kw2,
                                                       w1f, w2f, w3f, w2kf);
    hipMemsetAsync(h_mod + (size_t)N * C_DIM, 0, C_DIM * 2, stream);  // zero row N

    if (can_sort) {
        hipMemsetAsync(cnt, 0, ((size_t)N + 1) * 4, stream);
        k_hist<<<eb, 256, 0, stream>>>(ei + E, cnt, E);
        k_scan<<<1, 1024, 0, stream>>>(cnt, cursor, N);
        k_scatter<<<eb, 256, 0, stream>>>(ei, cursor, rank, src_sorted, E);
        k_edgek2<<<eb, 256, 0, stream>>>(rank, ea, kw1, kb1, w2kf, kb2,
                                         (u32*)k2h, E);
        k_conv3<<<N / 4, 256, 0, stream>>>(feats, h_mod, normv, cnt, src_sorted,
                                           k2h, w3f, kb3, cbias, tm2, ln2s, ln2b,
                                           out, xmb, N, q);
    } else {
        hipMemsetAsync(out, 0, (size_t)N * C_DIM * 4, stream);
        k_edge_atomic<<<eb, 256, 0, stream>>>(ei, ea, kw1, kb1, kw2, kb2, kw3, kb3,
                                              h_mod, out, E);
        int nc = N * C_DIM;
        k_finish<<<(nc + 255) / 256, 256, 0, stream>>>(feats, cbias, normv, out, nc);
        k_mod<true><<<N, C_DIM, 0, stream>>>(out, ln2s, ln2b, tm2, xmb, q);
    }

    k_ffn2<<<N / 64, 256, 0, stream>>>(xmb, w1f, mb1, w2f, mb2, out, N);
}

// Round 5
// 395.170 us; speedup vs baseline: 2.7306x; 1.0108x over previous
//
#include <hip/hip_runtime.h>
#include <hip/hip_bf16.h>

#define C_DIM 128
#define TWO_C 256
#define FC    32
#define T_DIM 512
#define NPW   8      // nodes per wave in k_conv3

typedef unsigned int   u32;
typedef unsigned short u16;
typedef short bf16x8 __attribute__((ext_vector_type(8)));
typedef float f32x4  __attribute__((ext_vector_type(4)));

__device__ __forceinline__ float fast_rcp(float x) {
    return __builtin_amdgcn_rcpf(x);          // v_rcp_f32, ~1 ULP
}
// gelu via A&S 7.1.27 rational erf (|eps_erf| <= 5e-4), 1/sqrt2 folded into coeffs.
__device__ __forceinline__ float gelu_f(float x) {
    float a = fabsf(x);
    float p = 1.0f + a * (0.19685352f + a * (0.11519450f +
              a * (3.4364302e-4f + a * 0.019527027f)));
    float d  = fast_rcp(p);
    float d2 = d * d;
    float d4 = d2 * d2;
    float s = 0.5f * x;
    return s + s * copysignf(1.0f - d4, x);
}
__device__ __forceinline__ u32 f2bf_bits(float x) {
    u32 u = __float_as_uint(x);
    return (u + 0x7fffu + ((u >> 16) & 1u)) >> 16;   // RNE f32->bf16
}
__device__ __forceinline__ float bf2f(u16 v) {
    return __uint_as_float((u32)v << 16);
}

// ---------- time modulation: tm = gelu(t) @ tw + tb, both mlps in one grid ----------
__global__ __launch_bounds__(256) void k_tmod(const float* __restrict__ t,
                                              const float* __restrict__ tw1,
                                              const float* __restrict__ tb1,
                                              float* __restrict__ tm1,
                                              const float* __restrict__ tw2,
                                              const float* __restrict__ tb2,
                                              float* __restrict__ tm2) {
    const float* tw = blockIdx.y ? tw2 : tw1;
    const float* tb = blockIdx.y ? tb2 : tb1;
    float*       tm = blockIdx.y ? tm2 : tm1;
    __shared__ float gt[T_DIM];
    int b = blockIdx.x;
    for (int k = threadIdx.x; k < T_DIM; k += 256)
        gt[k] = gelu_f(t[(size_t)b * T_DIM + k]);
    __syncthreads();
    int j = threadIdx.x;
    float acc = tb[j];
    for (int k = 0; k < T_DIM; ++k)
        acc += gt[k] * tw[(size_t)k * TWO_C + j];
    tm[(size_t)b * TWO_C + j] = acc;
}

// ---------- modulate: out = LN(in)*(1+scale) + shift ----------
// zrow: grid has one extra block that writes a zero row at index N (bf16 path).
template <bool BF16OUT, bool ZROW>
__global__ __launch_bounds__(C_DIM) void k_mod(const float* __restrict__ in,
                                               const float* __restrict__ lns,
                                               const float* __restrict__ lnb,
                                               const float* __restrict__ tm,
                                               void* __restrict__ outp, int q, int N) {
    int n = blockIdx.x, c = threadIdx.x;
    if (ZROW && n == N) {
        ((u16*)outp)[(size_t)N * C_DIM + c] = 0;
        return;
    }
    size_t o = (size_t)n * C_DIM + c;
    float v = in[o];
    float s1 = v, s2 = v * v;
#pragma unroll
    for (int off = 32; off > 0; off >>= 1) {
        s1 += __shfl_down(s1, off);
        s2 += __shfl_down(s2, off);
    }
    __shared__ float red[4];
    if ((c & 63) == 0) { red[(c >> 6) * 2] = s1; red[(c >> 6) * 2 + 1] = s2; }
    __syncthreads();
    float mean = (red[0] + red[2]) * (1.0f / C_DIM);
    float ex2  = (red[1] + red[3]) * (1.0f / C_DIM);
    float r    = rsqrtf(ex2 - mean * mean + 1e-5f);
    int b = n / q;
    float scale = tm[(size_t)b * TWO_C + c];
    float shift = tm[(size_t)b * TWO_C + C_DIM + c];
    float h = (v - mean) * r * lns[c] + lnb[c];
    float res = h * (1.0f + scale) + shift;
    if (BF16OUT) ((u16*)outp)[o] = (u16)f2bf_bits(res);
    else         ((float*)outp)[o] = res;
}

// ---------- counting sort by dst ----------
__global__ void k_hist(const int* __restrict__ dst, int* __restrict__ cnt, int E) {
    int e = blockIdx.x * 256 + threadIdx.x;
    if (e < E) atomicAdd(&cnt[dst[e]], 1);
}

__global__ __launch_bounds__(1024) void k_scan(int* __restrict__ data,
                                               int* __restrict__ cursor, int N) {
    __shared__ int tot[1024];
    int t = threadIdx.x;
    const int PER = 32;
    int base = t * PER;
    int loc[PER];
    int s = 0;
#pragma unroll
    for (int i = 0; i < PER; ++i) {
        int idx = base + i;
        int v = (idx < N) ? data[idx] : 0;
        loc[i] = s; s += v;
    }
    tot[t] = s;
    __syncthreads();
    for (int off = 1; off < 1024; off <<= 1) {
        int v = (t >= off) ? tot[t - off] : 0;
        __syncthreads();
        tot[t] += v;
        __syncthreads();
    }
    int bb = (t == 0) ? 0 : tot[t - 1];
#pragma unroll
    for (int i = 0; i < PER; ++i) {
        int idx = base + i;
        if (idx < N) { int v = bb + loc[i]; data[idx] = v; cursor[idx] = v; }
    }
    if (t == 1023) data[N] = tot[1023];
}

// scatter edge record {src, ax, ay, 0} into dst-sorted position (single 16B store)
__global__ void k_scatter(const int* __restrict__ ei, const float* __restrict__ ea,
                          int* __restrict__ cursor, int4* __restrict__ sed, int E) {
    int e = blockIdx.x * 256 + threadIdx.x;
    if (e < E) {
        int pos = atomicAdd(&cursor[ei[E + e]], 1);
        float2 av = ((const float2*)ea)[e];
        int4 v;
        v.x = ei[e];
        v.y = __float_as_int(av.x);
        v.z = __float_as_int(av.y);
        v.w = 0;
        sed[pos] = v;
    }
}

// ---------- prep: frag-major bf16 layouts ----------
// w1f/w2f (FFN): natural k. w3f: k permuted by pi(kk)=(kk>>1)+((kk&1)<<4) to match
// k2 (s, s+16) u32 packing. w2kf (edge layer2): natural k, [nt2][64][8].
#define PREP_TOT (32768 + 32768 + 4096 + 1024)
__global__ __launch_bounds__(256) void k_prep(const float* __restrict__ mw1,
                                              const float* __restrict__ mw2,
                                              const float* __restrict__ kw3,
                                              const float* __restrict__ kw2,
                                              u16* __restrict__ w1f,
                                              u16* __restrict__ w2f,
                                              u16* __restrict__ w3f,
                                              u16* __restrict__ w2kf) {
    int t = blockIdx.x * 256 + threadIdx.x;
    if (t < 32768) {            // w1f: [nt16][ks4][64][8], W = mw1 [128][256]
        int j = t & 7, l = (t >> 3) & 63, f = t >> 9;
        int ks = f & 3, nt = f >> 2;
        int k = ks * 32 + ((l >> 4) << 3) + j, n = nt * 16 + (l & 15);
        w1f[t] = (u16)f2bf_bits(mw1[(size_t)k * TWO_C + n]);
    } else if (t < 65536) {     // w2f: [nt8][ks8][64][8], W = mw2 [256][128]
        int t2 = t - 32768;
        int j = t2 & 7, l = (t2 >> 3) & 63, f = t2 >> 9;
        int ks = f & 7, nt = f >> 3;
        int k = ks * 32 + ((l >> 4) << 3) + j, n = nt * 16 + (l & 15);
        w2f[t2] = (u16)f2bf_bits(mw2[(size_t)k * C_DIM + n]);
    } else if (t < 69632) {     // w3f: [nt8][64][8], W = kw3 [32][128], k permuted
        int t3 = t - 65536;
        int j = t3 & 7, l = (t3 >> 3) & 63, nt = t3 >> 9;
        int kk = ((l >> 4) << 3) + j;
        int k = (kk >> 1) + ((kk & 1) << 4);
        int n = nt * 16 + (l & 15);
        w3f[t3] = (u16)f2bf_bits(kw3[(size_t)k * C_DIM + n]);
    } else if (t < PREP_TOT) {  // w2kf: [nt2][64][8], W = kw2 [32][32], natural k
        int t4 = t - 69632;
        int j = t4 & 7, l = (t4 >> 3) & 63, nt = t4 >> 9;
        int kk = ((l >> 4) << 3) + j;
        int n = nt * 16 + (l & 15);
        w2kf[t4] = (u16)f2bf_bits(kw2[(size_t)kk * FC + n]);
    }
}

// ---------- fused conv: edge-MLP (VALU+MFMA) + W=k2@w3 (MFMA) + gather + LN2+mod ----------
// LDS transpose swizzle: value (row, s) stored at col s ^ (((row>>1)&3)<<2).
__global__ __launch_bounds__(256, 4) void k_conv3(
        const float* __restrict__ feats,
        const u16* __restrict__ h_mod,        // (N+1) rows bf16, row N = zeros
        const float* __restrict__ normv,
        const int* __restrict__ start,
        const int4* __restrict__ sed,         // sorted {src, ax, ay, 0}
        const float* __restrict__ kw1, const float* __restrict__ kb1,
        const u16* __restrict__ w2kf, const float* __restrict__ kb2,
        const u16* __restrict__ w3f,  const float* __restrict__ kb3,
        const float* __restrict__ cbias,
        const float* __restrict__ tm2,
        const float* __restrict__ ln2s, const float* __restrict__ ln2b,
        float* __restrict__ xio,              // out: x = feats + conv (d_out)
        u16* __restrict__ xmb,                // out: modulate2(x) bf16
        int N, int q) {
    __shared__ u32 lds[4][16][16];
    int tid = threadIdx.x, wv = tid >> 6, l = tid & 63;
    int lr = l & 15, g = l >> 4;

    // persistent weight fragments
    bf16x8 w3b[8];
#pragma unroll
    for (int nt = 0; nt < 8; ++nt)
        w3b[nt] = *(const bf16x8*)(w3f + ((size_t)nt * 64 + l) * 8);
    bf16x8 w2b0 = *(const bf16x8*)(w2kf + (size_t)l * 8);
    bf16x8 w2b1 = *(const bf16x8*)(w2kf + (size_t)(64 + l) * 8);
    float b3c[8];
#pragma unroll
    for (int nt = 0; nt < 8; ++nt) b3c[nt] = kb3[nt * 16 + lr];
    float b2c0 = kb2[lr], b2c1 = kb2[16 + lr];
    float w1x[8], w1y[8], b1v[8];
#pragma unroll
    for (int j = 0; j < 8; ++j) {
        w1x[j] = kw1[8 * g + j];
        w1y[j] = kw1[FC + 8 * g + j];
        b1v[j] = kb1[8 * g + j];
    }
    const f32x4 zc = {0.f, 0.f, 0.f, 0.f};
    int gg = g ^ ((lr >> 1) & 3);             // swizzled read col-group

    int nbase = (blockIdx.x * 4 + wv) * NPW;
#pragma unroll 1
    for (int jn = 0; jn < NPW; ++jn) {
        int n = nbase + jn;
        if (n >= N) break;
        int s = start[n], e = start[n + 1];
        float acc[8] = {0.f, 0.f, 0.f, 0.f, 0.f, 0.f, 0.f, 0.f};

#pragma unroll 1
        for (int p0 = s; p0 < e; p0 += 16) {
            // edge record for A-row lr
            int pa = p0 + lr;
            float ax = 0.f, ay = 0.f;
            if (pa < e) {
                int4 ev = sed[pa];
                ax = __int_as_float(ev.y);
                ay = __int_as_float(ev.z);
            }
            // src for D-rows 4g+r
            int srcv[4];
#pragma unroll
            for (int r = 0; r < 4; ++r) {
                int pp = p0 + 4 * g + r;
                srcv[r] = (pp < e) ? sed[pp].x : N;
            }
            // layer1 in A-frag form: dims 8g..8g+7 of edge p0+lr
            union { u32 w[4]; bf16x8 v; } au;
#pragma unroll
            for (int m = 0; m < 4; ++m) {
                float v0 = gelu_f(fmaf(ax, w1x[2 * m],     fmaf(ay, w1y[2 * m],     b1v[2 * m])));
                float v1 = gelu_f(fmaf(ax, w1x[2 * m + 1], fmaf(ay, w1y[2 * m + 1], b1v[2 * m + 1])));
                au.w[m] = f2bf_bits(v0) | (f2bf_bits(v1) << 16);
            }
            // layer2 on MFMA, bias post-added
            f32x4 d0 = __builtin_amdgcn_mfma_f32_16x16x32_bf16(au.v, w2b0, zc, 0, 0, 0);
            f32x4 d1 = __builtin_amdgcn_mfma_f32_16x16x32_bf16(au.v, w2b1, zc, 0, 0, 0);
            // gelu + pack (dims lr, lr+16) + LDS transpose (swizzled)
#pragma unroll
            for (int r = 0; r < 4; ++r) {
                int row = 4 * g + r;
                u32 pk = f2bf_bits(gelu_f(d0[r] + b2c0)) |
                         (f2bf_bits(gelu_f(d1[r] + b2c1)) << 16);
                lds[wv][row][lr ^ (((row >> 1) & 3) << 2)] = pk;
            }
            __builtin_amdgcn_s_waitcnt(0xc07f);   // lgkmcnt(0): writes visible wave-wide
            bf16x8 a3 = *(const bf16x8*)&lds[wv][lr][4 * gg];
            // layer3: 8 MFMA + gather-accumulate; b3 applied via row-sum of h
#pragma unroll
            for (int nt = 0; nt < 8; ++nt) {
                f32x4 w = __builtin_amdgcn_mfma_f32_16x16x32_bf16(a3, w3b[nt], zc, 0, 0, 0);
                float h0 = bf2f(h_mod[(size_t)srcv[0] * C_DIM + nt * 16 + lr]);
                float h1 = bf2f(h_mod[(size_t)srcv[1] * C_DIM + nt * 16 + lr]);
                float h2 = bf2f(h_mod[(size_t)srcv[2] * C_DIM + nt * 16 + lr]);
                float h3 = bf2f(h_mod[(size_t)srcv[3] * C_DIM + nt * 16 + lr]);
                acc[nt] += w[0] * h0 + w[1] * h1 + w[2] * h2 + w[3] * h3;
                acc[nt] += b3c[nt] * (h0 + h1 + h2 + h3);
            }
        }
#pragma unroll
        for (int nt = 0; nt < 8; ++nt) {
            acc[nt] += __shfl_xor(acc[nt], 16, 64);
            acc[nt] += __shfl_xor(acc[nt], 32, 64);
        }

        float rnv = fast_rcp(normv[n]);
        float xv[8], m1 = 0.f, m2 = 0.f;
#pragma unroll
        for (int nt = 0; nt < 8; ++nt) {
            int c = nt * 16 + lr;
            float v = feats[(size_t)n * C_DIM + c] + (acc[nt] + cbias[c]) * rnv;
            xv[nt] = v; m1 += v; m2 += v * v;
        }
#pragma unroll
        for (int off = 1; off <= 8; off <<= 1) {
            m1 += __shfl_xor(m1, off, 64);
            m2 += __shfl_xor(m2, off, 64);
        }
        float mean = m1 * (1.0f / C_DIM);
        float rstd = rsqrtf(m2 * (1.0f / C_DIM) - mean * mean + 1e-5f);
        int b = n / q;
        bool wr = (g == 0);
#pragma unroll
        for (int nt = 0; nt < 8; ++nt) {
            int c = nt * 16 + lr;
            size_t o = (size_t)n * C_DIM + c;
            float sc = tm2[(size_t)b * TWO_C + c];
            float sh = tm2[(size_t)b * TWO_C + C_DIM + c];
            float h2 = ((xv[nt] - mean) * rstd * ln2s[c] + ln2b[c]) * (1.0f + sc) + sh;
            if (wr) { xio[o] = xv[nt]; xmb[o] = (u16)f2bf_bits(h2); }
        }
    }
}

// ---------- FFN (MFMA): out += gelu(xm@w1+b1)@w2+b2 ; per-wave 16 rows ----------
__global__ __launch_bounds__(256) void k_ffn2(const u16* __restrict__ xm,
                                              const u16* __restrict__ w1f,
                                              const float* __restrict__ b1,
                                              const u16* __restrict__ w2f,
                                              const float* __restrict__ b2,
                                              float* __restrict__ xio, int N) {
    __shared__ u16 sm[4][4096];                 // per-wave m tile [16][256] bf16
    int tid = threadIdx.x, w = tid >> 6, l = tid & 63;
    int lr = l & 15, g = l >> 4;
    int n0 = blockIdx.x * 64 + w * 16;
    u16* smw = sm[w];

    bf16x8 a[4];
    const u16* xrow = xm + (size_t)(n0 + lr) * C_DIM;
#pragma unroll
    for (int ks = 0; ks < 4; ++ks)
        a[ks] = *(const bf16x8*)(xrow + ks * 32 + g * 8);
    f32x4 acc[16];
#pragma unroll
    for (int nt = 0; nt < 16; ++nt) {
        float bv = b1[nt * 16 + lr];
        acc[nt][0] = bv; acc[nt][1] = bv; acc[nt][2] = bv; acc[nt][3] = bv;
    }
#pragma unroll
    for (int nt = 0; nt < 16; ++nt)
#pragma unroll
        for (int ks = 0; ks < 4; ++ks) {
            bf16x8 bfr = *(const bf16x8*)(w1f + ((size_t)(nt * 4 + ks) * 64 + l) * 8);
            acc[nt] = __builtin_amdgcn_mfma_f32_16x16x32_bf16(a[ks], bfr, acc[nt], 0, 0, 0);
        }
#pragma unroll
    for (int nt = 0; nt < 16; ++nt)
#pragma unroll
        for (int r = 0; r < 4; ++r) {
            int row = 4 * g + r, col = nt * 16 + lr;
            int byte = row * 512 + ((col * 2) ^ ((row & 7) << 4));
            smw[byte >> 1] = (u16)f2bf_bits(gelu_f(acc[nt][r]));
        }
    f32x4 acc2[8];
#pragma unroll
    for (int nt = 0; nt < 8; ++nt) {
        float bv = b2[nt * 16 + lr];
        acc2[nt][0] = bv; acc2[nt][1] = bv; acc2[nt][2] = bv; acc2[nt][3] = bv;
    }
#pragma unroll
    for (int ks = 0; ks < 8; ++ks) {
        int byte = lr * 512 + ((ks * 64 + g * 16) ^ ((lr & 7) << 4));
        bf16x8 a2 = *(const bf16x8*)(smw + (byte >> 1));
#pragma unroll
        for (int nt = 0; nt < 8; ++nt) {
            bf16x8 bfr = *(const bf16x8*)(w2f + ((size_t)(nt * 8 + ks) * 64 + l) * 8);
            acc2[nt] = __builtin_amdgcn_mfma_f32_16x16x32_bf16(a2, bfr, acc2[nt], 0, 0, 0);
        }
    }
#pragma unroll
    for (int nt = 0; nt < 8; ++nt)
#pragma unroll
        for (int r = 0; r < 4; ++r) {
            size_t o = (size_t)(n0 + 4 * g + r) * C_DIM + nt * 16 + lr;
            xio[o] += acc2[nt][r];
        }
}

// ---------- atomic fallback ----------
__global__ __launch_bounds__(256) void k_edge_atomic(
        const int* __restrict__ ei, const float* __restrict__ ea,
        const float* __restrict__ w1, const float* __restrict__ b1,
        const float* __restrict__ w2, const float* __restrict__ b2,
        const float* __restrict__ w3, const float* __restrict__ b3,
        const u16* __restrict__ h_mod, float* __restrict__ xacc, int E) {
    int e = blockIdx.x * 256 + threadIdx.x;
    if (e >= E) return;
    int src = ei[e], dst = ei[E + e];
    float ax = ea[(size_t)e * 2], ay = ea[(size_t)e * 2 + 1];
    float k1[FC];
#pragma unroll
    for (int i = 0; i < FC; ++i) k1[i] = gelu_f(ax * w1[i] + ay * w1[FC + i] + b1[i]);
    float k2v[FC];
#pragma unroll
    for (int j = 0; j < FC; ++j) {
        float acc = b2[j];
#pragma unroll
        for (int i = 0; i < FC; ++i) acc += k1[i] * w2[i * FC + j];
        k2v[j] = gelu_f(acc);
    }
    const u16* hrow = h_mod + (size_t)src * C_DIM;
    float* orow = xacc + (size_t)dst * C_DIM;
    for (int c = 0; c < C_DIM; ++c) {
        float wv = b3[c];
#pragma unroll
        for (int j = 0; j < FC; ++j) wv += k2v[j] * w3[j * C_DIM + c];
        atomicAdd(&orow[c], wv * bf2f(hrow[c]));
    }
}

__global__ void k_finish(const float* __restrict__ feats, const float* __restrict__ cbias,
                         const float* __restrict__ normv, float* __restrict__ xbuf, int NC) {
    int i = blockIdx.x * 256 + threadIdx.x;
    if (i >= NC) return;
    int c = i & (C_DIM - 1);
    int n = i >> 7;
    xbuf[i] = feats[i] + (xbuf[i] + cbias[c]) / normv[n];
}

extern "C" void kernel_launch(void* const* d_in, const int* in_sizes, int n_in,
                              void* d_out, int out_size, void* d_ws, size_t ws_size,
                              hipStream_t stream) {
    const float* feats = (const float*)d_in[0];
    const int*   ei    = (const int*)d_in[1];
    const float* ea    = (const float*)d_in[2];
    const float* t     = (const float*)d_in[3];
    const float* normv = (const float*)d_in[4];
    const float* ln1s  = (const float*)d_in[5];
    const float* ln1b  = (const float*)d_in[6];
    const float* ln2s  = (const float*)d_in[7];
    const float* ln2b  = (const float*)d_in[8];
    const float* tw1   = (const float*)d_in[9];
    const float* tb1   = (const float*)d_in[10];
    const float* tw2   = (const float*)d_in[11];
    const float* tb2   = (const float*)d_in[12];
    const float* kw1   = (const float*)d_in[13];
    const float* kb1   = (const float*)d_in[14];
    const float* kw2   = (const float*)d_in[15];
    const float* kb2   = (const float*)d_in[16];
    const float* kw3   = (const float*)d_in[17];
    const float* kb3   = (const float*)d_in[18];
    const float* cbias = (const float*)d_in[19];
    const float* mw1   = (const float*)d_in[20];
    const float* mb1   = (const float*)d_in[21];
    const float* mw2   = (const float*)d_in[22];
    const float* mb2   = (const float*)d_in[23];
    float* out = (float*)d_out;

    const int N = in_sizes[0] / C_DIM;
    const int E = in_sizes[1] / 2;
    const int B = in_sizes[3] / T_DIM;
    const int q = N / B;

    char* wp = (char*)d_ws;
    auto alloc = [&](size_t bytes) -> char* {
        char* p = wp; wp += (bytes + 255) & ~(size_t)255; return p;
    };
    float* tm1    = (float*)alloc((size_t)B * TWO_C * 4);
    float* tm2    = (float*)alloc((size_t)B * TWO_C * 4);
    u16*   h_mod  = (u16*)alloc(((size_t)N + 1) * C_DIM * 2);   // bf16, +1 zero row
    u16*   xmb    = (u16*)alloc((size_t)N * C_DIM * 2);
    u16*   w1f    = (u16*)alloc((size_t)C_DIM * TWO_C * 2);
    u16*   w2f    = (u16*)alloc((size_t)TWO_C * C_DIM * 2);
    u16*   w3f    = (u16*)alloc((size_t)FC * C_DIM * 2);
    u16*   w2kf   = (u16*)alloc((size_t)FC * FC * 2);
    int*   cnt    = (int*)alloc(((size_t)N + 1) * 4);
    int*   cursor = (int*)alloc((size_t)N * 4);
    size_t fixed = (size_t)(wp - (char*)d_ws);
    bool can_sort = ws_size >= fixed + ((size_t)E + 16) * 16;
    int4* sed = (int4*)alloc(((size_t)E + 16) * 16);

    const int eb = (E + 255) / 256;

    k_tmod<<<dim3(B, 2), 256, 0, stream>>>(t, tw1, tb1, tm1, tw2, tb2, tm2);
    k_mod<true, true><<<N + 1, C_DIM, 0, stream>>>(feats, ln1s, ln1b, tm1, h_mod, q, N);
    k_prep<<<(PREP_TOT + 255) / 256, 256, 0, stream>>>(mw1, mw2, kw3, kw2,
                                                       w1f, w2f, w3f, w2kf);

    if (can_sort) {
        hipMemsetAsync(cnt, 0, ((size_t)N + 1) * 4, stream);
        k_hist<<<eb, 256, 0, stream>>>(ei + E, cnt, E);
        k_scan<<<1, 1024, 0, stream>>>(cnt, cursor, N);
        k_scatter<<<eb, 256, 0, stream>>>(ei, ea, cursor, sed, E);
        int cb = (N + 4 * NPW - 1) / (4 * NPW);
        k_conv3<<<cb, 256, 0, stream>>>(feats, h_mod, normv, cnt, sed,
                                        kw1, kb1, w2kf, kb2, w3f, kb3, cbias,
                                        tm2, ln2s, ln2b, out, xmb, N, q);
    } else {
        hipMemsetAsync(out, 0, (size_t)N * C_DIM * 4, stream);
        k_edge_atomic<<<eb, 256, 0, stream>>>(ei, ea, kw1, kb1, kw2, kb2, kw3, kb3,
                                              h_mod, out, E);
        int nc = N * C_DIM;
        k_finish<<<(nc + 255) / 256, 256, 0, stream>>>(feats, cbias, normv, out, nc);
        k_mod<true, false><<<N, C_DIM, 0, stream>>>(out, ln2s, ln2b, tm2, xmb, q, N);
    }

    k_ffn2<<<N / 64, 256, 0, stream>>>(xmb, w1f, mb1, w2f, mb2, out, N);
}